// Round 1
// baseline (223.993 us; speedup 1.0000x reference)
//
#include <hip/hip_runtime.h>

// Problem constants (hardcoded from reference; spatial_shapes = [[4,8]]*4)
//  bs=64, nq=64, E=256, Hn=8, dh=32, L=4, P=16, BEV=2, Pb=32
//  qb=128 collapses to 64 (queries duplicated), H=4, W=8 per level.
//  OFF column for (h,f,c) = h*256 + 2f + c; rp level = f&3; image level = f>>5;
//  attention key index = f.  Final output pairs (2q,2q+1) mod 64.

// ---------------------------------------------------------------------------
// Kernel A: OFF[4096][2048] = query[4096][256] @ W_off[256][2048] + b_off
// fp32 tiled SGEMM, 64x64 tile, KC=32, 4x4 per thread.
// ---------------------------------------------------------------------------
__global__ __launch_bounds__(256, 4) void offs_gemm(
    const float* __restrict__ A, const float* __restrict__ W,
    const float* __restrict__ bias, float* __restrict__ C)
{
    __shared__ float As[32][68];  // [k][m] (transposed)
    __shared__ float Ws[32][68];  // [k][n]
    const int n0 = blockIdx.x * 64;
    const int m0 = blockIdx.y * 64;
    const int t  = threadIdx.x;
    const int tx = t & 15, ty = t >> 4;

    float acc[4][4] = {};
    for (int kc = 0; kc < 256; kc += 32) {
        {
            const int r = t >> 3, c4 = (t & 7) * 4;
            #pragma unroll
            for (int pass = 0; pass < 2; ++pass) {
                const int m = r + pass * 32;
                const float4 v = *(const float4*)(A + (size_t)(m0 + m) * 256 + kc + c4);
                As[c4 + 0][m] = v.x; As[c4 + 1][m] = v.y;
                As[c4 + 2][m] = v.z; As[c4 + 3][m] = v.w;
            }
            const int kr = t >> 4, c4w = (t & 15) * 4;
            #pragma unroll
            for (int pass = 0; pass < 2; ++pass) {
                const int kk = kr + pass * 16;
                *(float4*)(&Ws[kk][c4w]) =
                    *(const float4*)(W + (size_t)(kc + kk) * 2048 + n0 + c4w);
            }
        }
        __syncthreads();
        #pragma unroll
        for (int kk = 0; kk < 32; ++kk) {
            const float4 a = *(const float4*)(&As[kk][ty * 4]);
            const float4 b = *(const float4*)(&Ws[kk][tx * 4]);
            const float av[4] = {a.x, a.y, a.z, a.w};
            const float bv[4] = {b.x, b.y, b.z, b.w};
            #pragma unroll
            for (int i = 0; i < 4; ++i)
                #pragma unroll
                for (int j = 0; j < 4; ++j)
                    acc[i][j] += av[i] * bv[j];
        }
        __syncthreads();
    }
    const float4 bv4 = *(const float4*)(bias + n0 + tx * 4);
    const float bb[4] = {bv4.x, bv4.y, bv4.z, bv4.w};
    #pragma unroll
    for (int i = 0; i < 4; ++i) {
        const int row = m0 + ty * 4 + i;
        float4 o;
        o.x = acc[i][0] + bb[0]; o.y = acc[i][1] + bb[1];
        o.z = acc[i][2] + bb[2]; o.w = acc[i][3] + bb[3];
        *(float4*)(C + (size_t)row * 2048 + n0 + tx * 4) = o;
    }
}

// ---------------------------------------------------------------------------
// Kernel B: fused attention + bilinear-scatter + AV + pair-mean + residual.
// Grid: (h=8, b=64, s=2) ; 256 threads; 32 queries per block.
// ---------------------------------------------------------------------------
__global__ __launch_bounds__(256, 2) void fused_tsa(
    const float* __restrict__ query, const float* __restrict__ key_hist,
    const float* __restrict__ value_hist, const float* __restrict__ refp,
    const float* __restrict__ OFF, float* __restrict__ out)
{
    const int h  = blockIdx.x;   // 0..7
    const int b  = blockIdx.y;   // 0..63
    const int s  = blockIdx.z;   // 0..1
    const int q0 = s * 32;
    const int t  = threadIdx.x;

    // pool holds ks_t[32][128] + qs_t[32][32] during logits, then Am[32][132]
    __shared__ float pool[32 * 128 + 32 * 32];      // 5120 floats
    __shared__ float vs[128][36];                   // [k][d]
    __shared__ float att[32][128];                  // [q][k]
    __shared__ float rps[32][8];                    // [q][l*2+c]
    __shared__ float red[32][8];
    __shared__ float rowmax[32];
    __shared__ float invsum[32];

    float (*ks_t)[128] = (float (*)[128])pool;            // [d][k]
    float (*qs_t)[32]  = (float (*)[32])(pool + 4096);    // [d][q]
    float (*Am)[132]   = (float (*)[132])pool;            // [q][pos] (aliases ks_t/qs_t)

    // ---- stage loads ----
    {
        const int q = t & 31, v4 = t >> 5;  // v4 in 0..7
        const float4 v = *(const float4*)(query +
            (size_t)(b * 64 + q0 + q) * 256 + h * 32 + v4 * 4);
        qs_t[v4 * 4 + 0][q] = v.x; qs_t[v4 * 4 + 1][q] = v.y;
        qs_t[v4 * 4 + 2][q] = v.z; qs_t[v4 * 4 + 3][q] = v.w;
    }
    {
        const int kq = t & 31, v4 = t >> 5;
        #pragma unroll
        for (int p = 0; p < 4; ++p) {
            const int krow = p * 32 + kq;
            const size_t roff = (krow < 64)
                ? (size_t)(b * 64 + krow) * 256
                : (size_t)(b * 64 + krow - 64) * 256;
            const float* srck = (krow < 64) ? query : key_hist;
            const float* srcv = (krow < 64) ? query : value_hist;
            const float4 kv = *(const float4*)(srck + roff + h * 32 + v4 * 4);
            ks_t[v4 * 4 + 0][krow] = kv.x; ks_t[v4 * 4 + 1][krow] = kv.y;
            ks_t[v4 * 4 + 2][krow] = kv.z; ks_t[v4 * 4 + 3][krow] = kv.w;
            *(float4*)(&vs[krow][v4 * 4]) =
                *(const float4*)(srcv + roff + h * 32 + v4 * 4);
        }
    }
    {
        const int q = t >> 3, j = t & 7;
        rps[q][j] = refp[(size_t)(b * 64 + q0 + q) * 8 + j];
    }
    __syncthreads();

    // ---- logits: att[q][k] = sum_d qs_t[d][q] * ks_t[d][k]  (4x4 tiles) ----
    {
        const int qt = (t >> 5) * 4;   // 0..28
        const int kt = (t & 31) * 4;   // 0..124
        float accl[4][4] = {};
        #pragma unroll
        for (int dd = 0; dd < 32; ++dd) {
            const float4 qv = *(const float4*)(&qs_t[dd][qt]);
            const float4 kv = *(const float4*)(&ks_t[dd][kt]);
            const float qa[4] = {qv.x, qv.y, qv.z, qv.w};
            const float ka[4] = {kv.x, kv.y, kv.z, kv.w};
            #pragma unroll
            for (int i = 0; i < 4; ++i)
                #pragma unroll
                for (int j = 0; j < 4; ++j)
                    accl[i][j] += qa[i] * ka[j];
        }
        #pragma unroll
        for (int i = 0; i < 4; ++i)
            #pragma unroll
            for (int j = 0; j < 4; ++j)
                att[qt + i][kt + j] = accl[i][j];
    }
    __syncthreads();

    // ---- zero Am (aliases ks_t/qs_t — dead after logits) ----
    for (int idx = t; idx < 32 * 132; idx += 256) pool[idx] = 0.f;

    // ---- softmax over k=128 per q-row (8 threads/row) ----
    {
        const int q = t >> 3, part = t & 7;
        const int k0 = part * 16;
        float m = -1e30f;
        #pragma unroll
        for (int k = 0; k < 16; ++k) m = fmaxf(m, att[q][k0 + k]);
        red[q][part] = m;
        __syncthreads();
        if (part == 0) {
            float M = red[q][0];
            #pragma unroll
            for (int p = 1; p < 8; ++p) M = fmaxf(M, red[q][p]);
            rowmax[q] = M;
        }
        __syncthreads();
        const float M = rowmax[q];
        float ssum = 0.f;
        #pragma unroll
        for (int k = 0; k < 16; ++k) {
            const float e = __expf(att[q][k0 + k] - M);
            att[q][k0 + k] = e;
            ssum += e;
        }
        red[q][part] = ssum;
        __syncthreads();
        if (part == 0) {
            float S = red[q][0];
            #pragma unroll
            for (int p = 1; p < 8; ++p) S += red[q][p];
            invsum[q] = 1.0f / S;
        }
        __syncthreads();
    }

    // ---- A-build: scatter attn*bilinear-weights into Am[q][valuepos] ----
    {
        const int q = t >> 3, fg = t & 7;
        const float* offrow = OFF + (size_t)(b * 64 + q0 + q) * 2048 + h * 256;
        const float isum = invsum[q];
        float* row = Am[q];
        for (int i = 0; i < 16; ++i) {
            const int f = fg * 16 + i;
            const float a = att[q][f] * isum;
            const float2 o = *(const float2*)(offrow + 2 * f);
            const int l = f & 3;
            const float locx = rps[q][l * 2 + 0] + o.x * 0.125f;
            const float locy = rps[q][l * 2 + 1] + o.y * 0.25f;
            const float gx = 8.f * locx - 0.5f;   // (2*loc-1+1)*W/2-0.5, W=8
            const float gy = 4.f * locy - 0.5f;   // H=4
            const float x0f = floorf(gx), y0f = floorf(gy);
            const float wx = gx - x0f, wy = gy - y0f;
            const int x0 = (int)x0f, y0 = (int)y0f;
            const int base = (f >> 5) * 32;       // image level = f>>5
            const bool xv0 = (x0 >= 0) && (x0 < 8);
            const bool xv1 = (x0 >= -1) && (x0 < 7);
            const bool yv0 = (y0 >= 0) && (y0 < 4);
            const bool yv1 = (y0 >= -1) && (y0 < 3);
            if (xv0 && yv0) atomicAdd(&row[base + y0 * 8 + x0],           a * (1.f - wx) * (1.f - wy));
            if (xv1 && yv0) atomicAdd(&row[base + y0 * 8 + x0 + 1],       a * wx * (1.f - wy));
            if (xv0 && yv1) atomicAdd(&row[base + (y0 + 1) * 8 + x0],     a * (1.f - wx) * wy);
            if (xv1 && yv1) atomicAdd(&row[base + (y0 + 1) * 8 + x0 + 1], a * wx * wy);
        }
    }
    __syncthreads();

    // ---- AV: res[q][d] = sum_p Am[q][p] * vs[p][d]; pair-mean; +query ----
    {
        const int d4 = (t & 7) * 4;
        const int q  = t >> 3;
        float acc[4] = {0.f, 0.f, 0.f, 0.f};
        #pragma unroll 4
        for (int p = 0; p < 128; ++p) {
            const float a = Am[q][p];
            const float4 v = *(const float4*)(&vs[p][d4]);
            acc[0] += a * v.x; acc[1] += a * v.y;
            acc[2] += a * v.z; acc[3] += a * v.w;
        }
        float avg[4];
        #pragma unroll
        for (int j = 0; j < 4; ++j)
            avg[j] = 0.5f * (acc[j] + __shfl_xor(acc[j], 8, 64));
        const int qg  = q0 + q;
        const int pj  = qg >> 1;
        const int row = (qg & 1) ? (pj + 32) : pj;
        const float4 qv = *(const float4*)(query +
            (size_t)(b * 64 + row) * 256 + h * 32 + d4);
        float4 o;
        o.x = qv.x + avg[0]; o.y = qv.y + avg[1];
        o.z = qv.z + avg[2]; o.w = qv.w + avg[3];
        *(float4*)(out + (size_t)(b * 64 + row) * 256 + h * 32 + d4) = o;
    }
}

extern "C" void kernel_launch(void* const* d_in, const int* in_sizes, int n_in,
                              void* d_out, int out_size, void* d_ws, size_t ws_size,
                              hipStream_t stream) {
    (void)in_sizes; (void)n_in; (void)out_size; (void)ws_size;
    const float* query      = (const float*)d_in[0];
    const float* key_hist   = (const float*)d_in[1];
    const float* value_hist = (const float*)d_in[2];
    const float* refp       = (const float*)d_in[3];
    // d_in[4] spatial_shapes unused (hardcoded 4x8)
    const float* W_off      = (const float*)d_in[5];
    const float* b_off      = (const float*)d_in[6];
    float* OFF = (float*)d_ws;            // 4096 x 2048 fp32 = 33.5 MB
    float* out = (float*)d_out;

    offs_gemm<<<dim3(32, 64), 256, 0, stream>>>(query, W_off, b_off, OFF);
    fused_tsa<<<dim3(8, 64, 2), 256, 0, stream>>>(query, key_hist, value_hist,
                                                  refp, OFF, out);
}

// Round 2
// 178.450 us; speedup vs baseline: 1.2552x; 1.2552x over previous
//
#include <hip/hip_runtime.h>

// Problem constants (hardcoded; spatial_shapes = [[4,8]]*4)
//  bs=64, nq=64, E=256, Hn=8, dh=32, L=4, P=16, BEV=2, Pb=32
//  qb=128 collapses to 64 (queries duplicated). OFF col (h,f,c)=h*256+2f+c;
//  rp level = f&3; image level = f>>5; attn key = f; output pairs (2q,2q+1)%64.
//
// ws layout: [0,2MB) Ab bf16 4096x256 | [2MB,3MB) Wt bf16 2048x256 (W^T)
//            [3MB,19.75MB) OFFb bf16 4096x2048

typedef short  s16x8 __attribute__((ext_vector_type(8)));
typedef short  s16x4 __attribute__((ext_vector_type(4)));
typedef float  f32x4 __attribute__((ext_vector_type(4)));

__device__ __forceinline__ unsigned short f2bf(float f) {
    union { float f; unsigned u; } v; v.f = f;
    unsigned r = v.u + 0x7FFFu + ((v.u >> 16) & 1u);   // round-to-nearest-even
    return (unsigned short)(r >> 16);
}

// ---------------------------------------------------------------------------
// query (4096x256 f32) -> bf16
// ---------------------------------------------------------------------------
__global__ __launch_bounds__(256) void conv_bf16(const float* __restrict__ in,
                                                 short* __restrict__ out) {
    const int i4 = (blockIdx.x * 256 + threadIdx.x) * 4;
    const float4 v = *(const float4*)(in + i4);
    s16x4 o;
    o.x = (short)f2bf(v.x); o.y = (short)f2bf(v.y);
    o.z = (short)f2bf(v.z); o.w = (short)f2bf(v.w);
    *(s16x4*)(out + i4) = o;
}

// ---------------------------------------------------------------------------
// W_off [256][2048] f32 -> Wt [2048][256] bf16 (32x32 LDS tile transpose)
// ---------------------------------------------------------------------------
__global__ __launch_bounds__(256) void transp_bf16(const float* __restrict__ W,
                                                   short* __restrict__ Wt) {
    __shared__ float s[32][33];
    const int n0 = blockIdx.x * 32, k0 = blockIdx.y * 32;
    const int c = threadIdx.x & 31, r0 = threadIdx.x >> 5;
    #pragma unroll
    for (int p = 0; p < 4; ++p) {
        const int r = r0 + p * 8;
        s[r][c] = W[(size_t)(k0 + r) * 2048 + n0 + c];
    }
    __syncthreads();
    #pragma unroll
    for (int p = 0; p < 4; ++p) {
        const int r = r0 + p * 8;
        Wt[(size_t)(n0 + r) * 256 + k0 + c] = (short)f2bf(s[c][r]);
    }
}

// ---------------------------------------------------------------------------
// OFFb[4096][2048] = bf16( Ab[4096][256] @ Wt^T + bias )
// 128x128 tile, 4 waves in 2x2, each wave 4x4 of 16x16x32 bf16 MFMA.
// LDS rows padded to 40 shorts: frag b128 reads word-offsets 4*(5r+q) ->
// 64 distinct, 8 words/bank uniform = conflict-free.
// ---------------------------------------------------------------------------
__global__ __launch_bounds__(256) void offs_gemm_mfma(
    const short* __restrict__ Ab, const short* __restrict__ Wt,
    const float* __restrict__ bias, short* __restrict__ OFFb)
{
    __shared__ __align__(16) short Asl[128][40];
    __shared__ __align__(16) short Bsl[128][40];
    const int n0 = blockIdx.x * 128, m0 = blockIdx.y * 128;
    const int t = threadIdx.x, lane = t & 63, wave = t >> 6;
    const int wm0 = (wave >> 1) * 64, wn0 = (wave & 1) * 64;
    const int r = lane & 15, q = lane >> 4;

    f32x4 acc[4][4] = {};

    for (int kc = 0; kc < 256; kc += 32) {
        #pragma unroll
        for (int ss = 0; ss < 2; ++ss) {
            const int seg = t + ss * 256;
            const int row = seg >> 2, off8 = (seg & 3) * 8;
            *(s16x8*)&Asl[row][off8] =
                *(const s16x8*)(Ab + (size_t)(m0 + row) * 256 + kc + off8);
            *(s16x8*)&Bsl[row][off8] =
                *(const s16x8*)(Wt + (size_t)(n0 + row) * 256 + kc + off8);
        }
        __syncthreads();
        s16x8 af[4], bf[4];
        #pragma unroll
        for (int i = 0; i < 4; ++i) {
            af[i] = *(const s16x8*)&Asl[wm0 + i * 16 + r][q * 8];
            bf[i] = *(const s16x8*)&Bsl[wn0 + i * 16 + r][q * 8];
        }
        #pragma unroll
        for (int i = 0; i < 4; ++i)
            #pragma unroll
            for (int j = 0; j < 4; ++j)
                acc[i][j] = __builtin_amdgcn_mfma_f32_16x16x32_bf16(
                    af[i], bf[j], acc[i][j], 0, 0, 0);
        __syncthreads();
    }

    // C/D: col = lane&15, row = (lane>>4)*4 + reg  [m89-verified]
    #pragma unroll
    for (int j = 0; j < 4; ++j) {
        const int col = n0 + wn0 + j * 16 + r;
        const float bb = bias[col];
        #pragma unroll
        for (int i = 0; i < 4; ++i) {
            const int rowg = m0 + wm0 + i * 16 + q * 4;
            #pragma unroll
            for (int rg = 0; rg < 4; ++rg)
                OFFb[(size_t)(rowg + rg) * 2048 + col] =
                    (short)f2bf(acc[i][j][rg] + bb);
        }
    }
}

// ---------------------------------------------------------------------------
// Kernel B: fused attention + bilinear-scatter + AV + pair-mean + residual.
// Grid: (h=8, b=64, s=2) ; 256 threads; 32 queries per block.
// ---------------------------------------------------------------------------
__global__ __launch_bounds__(256, 2) void fused_tsa(
    const float* __restrict__ query, const float* __restrict__ key_hist,
    const float* __restrict__ value_hist, const float* __restrict__ refp,
    const unsigned short* __restrict__ OFFb, float* __restrict__ out)
{
    const int h  = blockIdx.x;   // 0..7
    const int b  = blockIdx.y;   // 0..63
    const int s  = blockIdx.z;   // 0..1
    const int q0 = s * 32;
    const int t  = threadIdx.x;

    __shared__ float pool[32 * 128 + 32 * 32];      // 5120 floats
    __shared__ float vs[128][36];                   // [k][d]
    __shared__ float att[32][128];                  // [q][k]
    __shared__ float rps[32][8];                    // [q][l*2+c]
    __shared__ float red[32][8];
    __shared__ float rowmax[32];
    __shared__ float invsum[32];

    float (*ks_t)[128] = (float (*)[128])pool;            // [d][k]
    float (*qs_t)[32]  = (float (*)[32])(pool + 4096);    // [d][q]
    float (*Am)[132]   = (float (*)[132])pool;            // [q][pos] (aliases)

    // ---- stage loads ----
    {
        const int q = t & 31, v4 = t >> 5;
        const float4 v = *(const float4*)(query +
            (size_t)(b * 64 + q0 + q) * 256 + h * 32 + v4 * 4);
        qs_t[v4 * 4 + 0][q] = v.x; qs_t[v4 * 4 + 1][q] = v.y;
        qs_t[v4 * 4 + 2][q] = v.z; qs_t[v4 * 4 + 3][q] = v.w;
    }
    {
        const int kq = t & 31, v4 = t >> 5;
        #pragma unroll
        for (int p = 0; p < 4; ++p) {
            const int krow = p * 32 + kq;
            const size_t roff = (krow < 64)
                ? (size_t)(b * 64 + krow) * 256
                : (size_t)(b * 64 + krow - 64) * 256;
            const float* srck = (krow < 64) ? query : key_hist;
            const float* srcv = (krow < 64) ? query : value_hist;
            const float4 kv = *(const float4*)(srck + roff + h * 32 + v4 * 4);
            ks_t[v4 * 4 + 0][krow] = kv.x; ks_t[v4 * 4 + 1][krow] = kv.y;
            ks_t[v4 * 4 + 2][krow] = kv.z; ks_t[v4 * 4 + 3][krow] = kv.w;
            *(float4*)(&vs[krow][v4 * 4]) =
                *(const float4*)(srcv + roff + h * 32 + v4 * 4);
        }
    }
    {
        const int q = t >> 3, j = t & 7;
        rps[q][j] = refp[(size_t)(b * 64 + q0 + q) * 8 + j];
    }
    __syncthreads();

    // ---- logits ----
    {
        const int qt = (t >> 5) * 4;
        const int kt = (t & 31) * 4;
        float accl[4][4] = {};
        #pragma unroll
        for (int dd = 0; dd < 32; ++dd) {
            const float4 qv = *(const float4*)(&qs_t[dd][qt]);
            const float4 kv = *(const float4*)(&ks_t[dd][kt]);
            const float qa[4] = {qv.x, qv.y, qv.z, qv.w};
            const float ka[4] = {kv.x, kv.y, kv.z, kv.w};
            #pragma unroll
            for (int i = 0; i < 4; ++i)
                #pragma unroll
                for (int j = 0; j < 4; ++j)
                    accl[i][j] += qa[i] * ka[j];
        }
        #pragma unroll
        for (int i = 0; i < 4; ++i)
            #pragma unroll
            for (int j = 0; j < 4; ++j)
                att[qt + i][kt + j] = accl[i][j];
    }
    __syncthreads();

    // ---- zero Am ----
    for (int idx = t; idx < 32 * 132; idx += 256) pool[idx] = 0.f;

    // ---- softmax ----
    {
        const int q = t >> 3, part = t & 7;
        const int k0 = part * 16;
        float m = -1e30f;
        #pragma unroll
        for (int k = 0; k < 16; ++k) m = fmaxf(m, att[q][k0 + k]);
        red[q][part] = m;
        __syncthreads();
        if (part == 0) {
            float M = red[q][0];
            #pragma unroll
            for (int p = 1; p < 8; ++p) M = fmaxf(M, red[q][p]);
            rowmax[q] = M;
        }
        __syncthreads();
        const float M = rowmax[q];
        float ssum = 0.f;
        #pragma unroll
        for (int k = 0; k < 16; ++k) {
            const float e = __expf(att[q][k0 + k] - M);
            att[q][k0 + k] = e;
            ssum += e;
        }
        red[q][part] = ssum;
        __syncthreads();
        if (part == 0) {
            float S = red[q][0];
            #pragma unroll
            for (int p = 1; p < 8; ++p) S += red[q][p];
            invsum[q] = 1.0f / S;
        }
        __syncthreads();
    }

    // ---- A-build: scatter attn*bilinear into Am[q][pos]; OFFb bf16-packed ----
    {
        const int q = t >> 3, fg = t & 7;
        const unsigned int* offrow = (const unsigned int*)(OFFb +
            (size_t)(b * 64 + q0 + q) * 2048 + h * 256);
        const float isum = invsum[q];
        float* row = Am[q];
        for (int i = 0; i < 16; ++i) {
            const int f = fg + 8 * i;          // lanes within a q read consecutive
            const unsigned int u = offrow[f];  // lo = x bf16, hi = y bf16
            const float oxv = __uint_as_float(u << 16);
            const float oyv = __uint_as_float(u & 0xFFFF0000u);
            const float a = att[q][f] * isum;
            const int l = f & 3;
            const float locx = rps[q][l * 2 + 0] + oxv * 0.125f;
            const float locy = rps[q][l * 2 + 1] + oyv * 0.25f;
            const float gx = 8.f * locx - 0.5f;
            const float gy = 4.f * locy - 0.5f;
            const float x0f = floorf(gx), y0f = floorf(gy);
            const float wx = gx - x0f, wy = gy - y0f;
            const int x0 = (int)x0f, y0 = (int)y0f;
            const int base = (f >> 5) * 32;
            const bool xv0 = (x0 >= 0) && (x0 < 8);
            const bool xv1 = (x0 >= -1) && (x0 < 7);
            const bool yv0 = (y0 >= 0) && (y0 < 4);
            const bool yv1 = (y0 >= -1) && (y0 < 3);
            if (xv0 && yv0) atomicAdd(&row[base + y0 * 8 + x0],           a * (1.f - wx) * (1.f - wy));
            if (xv1 && yv0) atomicAdd(&row[base + y0 * 8 + x0 + 1],       a * wx * (1.f - wy));
            if (xv0 && yv1) atomicAdd(&row[base + (y0 + 1) * 8 + x0],     a * (1.f - wx) * wy);
            if (xv1 && yv1) atomicAdd(&row[base + (y0 + 1) * 8 + x0 + 1], a * wx * wy);
        }
    }
    __syncthreads();

    // ---- AV + pair-mean + residual ----
    {
        const int d4 = (t & 7) * 4;
        const int q  = t >> 3;
        float acc[4] = {0.f, 0.f, 0.f, 0.f};
        #pragma unroll 4
        for (int p = 0; p < 128; ++p) {
            const float a = Am[q][p];
            const float4 v = *(const float4*)(&vs[p][d4]);
            acc[0] += a * v.x; acc[1] += a * v.y;
            acc[2] += a * v.z; acc[3] += a * v.w;
        }
        float avg[4];
        #pragma unroll
        for (int j = 0; j < 4; ++j)
            avg[j] = 0.5f * (acc[j] + __shfl_xor(acc[j], 8, 64));
        const int qg  = q0 + q;
        const int pj  = qg >> 1;
        const int row = (qg & 1) ? (pj + 32) : pj;
        const float4 qv = *(const float4*)(query +
            (size_t)(b * 64 + row) * 256 + h * 32 + d4);
        float4 o;
        o.x = qv.x + avg[0]; o.y = qv.y + avg[1];
        o.z = qv.z + avg[2]; o.w = qv.w + avg[3];
        *(float4*)(out + (size_t)(b * 64 + row) * 256 + h * 32 + d4) = o;
    }
}

extern "C" void kernel_launch(void* const* d_in, const int* in_sizes, int n_in,
                              void* d_out, int out_size, void* d_ws, size_t ws_size,
                              hipStream_t stream) {
    (void)in_sizes; (void)n_in; (void)out_size; (void)ws_size;
    const float* query      = (const float*)d_in[0];
    const float* key_hist   = (const float*)d_in[1];
    const float* value_hist = (const float*)d_in[2];
    const float* refp       = (const float*)d_in[3];
    const float* W_off      = (const float*)d_in[5];
    const float* b_off      = (const float*)d_in[6];

    char* ws = (char*)d_ws;
    short* Ab   = (short*)(ws);                       // 2 MB
    short* Wt   = (short*)(ws + (2u << 20));          // 1 MB
    short* OFFb = (short*)(ws + (3u << 20));          // 16.75 MB
    float* out  = (float*)d_out;

    conv_bf16<<<1024, 256, 0, stream>>>(query, Ab);
    transp_bf16<<<dim3(64, 8), 256, 0, stream>>>(W_off, Wt);
    offs_gemm_mfma<<<dim3(16, 32), 256, 0, stream>>>(Ab, Wt, b_off, OFFb);
    fused_tsa<<<dim3(8, 64, 2), 256, 0, stream>>>(query, key_hist, value_hist,
                                                  refp, (const unsigned short*)OFFb,
                                                  out);
}